// Round 2
// baseline (586.221 us; speedup 1.0000x reference)
//
#include <hip/hip_runtime.h>
#include <hip/hip_fp16.h>

#define N    8192
#define FIN  256
#define FOUT 128
#define BM   64
#define BN   64

typedef _Float16 half8 __attribute__((ext_vector_type(8)));
typedef _Float16 half4v __attribute__((ext_vector_type(4)));
typedef float floatx4 __attribute__((ext_vector_type(4)));

// ---------------------------------------------------------------------------
// Kernel W-prep: WT[w][n][k] = fp16(W_w[k][n]); 3 x 128 x 256 fp16 (192 KB).
// ---------------------------------------------------------------------------
__global__ __launch_bounds__(256)
void wprep_kernel(const float* __restrict__ W0,
                  const float* __restrict__ W1,
                  const float* __restrict__ W2,
                  _Float16* __restrict__ WT)
{
    int idx = blockIdx.x * 256 + threadIdx.x;       // 3*256*128 threads
    int w = idx >> 15;
    int rem = idx & 32767;
    int k = rem >> 7;                                // [0,256)
    int n = rem & 127;                               // [0,128) consecutive -> coalesced read
    const float* Wp = w == 0 ? W0 : (w == 1 ? W1 : W2);
    WT[(size_t)w * 32768 + (size_t)n * FIN + k] = (_Float16)Wp[(size_t)k * FOUT + n];
}

// ---------------------------------------------------------------------------
// Kernel A: H = fp16(inp@W), H2 = fp16(inp@W2), H3T = fp16((inp@W3)^T)
// No LDS, no barriers. A-frags from inp (fp32->fp16 in reg), B-frags from WT
// (64 KB per matrix, L1/L2-hot). grid (N/64, 3), block 256.
// ---------------------------------------------------------------------------
__global__ __launch_bounds__(256, 2)
void gemm3_kernel(const float* __restrict__ inp,
                  const _Float16* __restrict__ WT,
                  _Float16* __restrict__ H,
                  _Float16* __restrict__ H2,
                  _Float16* __restrict__ H3T)
{
    const int which = blockIdx.y;
    const _Float16* WTw = WT + (size_t)which * 32768;
    const int r0 = blockIdx.x * 64;
    const int tid  = threadIdx.x;
    const int wave = tid >> 6;
    const int lane = tid & 63;
    const int lo16 = lane & 15;
    const int quad = lane >> 4;
    const int r = r0 + wave * 16 + lo16;

    // preload + convert A fragments: a[kc][j] = inp[r][kc*32 + quad*8 + j]
    half8 a[8];
#pragma unroll
    for (int kc = 0; kc < 8; kc++) {
        const float* p = &inp[(size_t)r * FIN + kc * 32 + quad * 8];
        float4 v0 = *(const float4*)p;
        float4 v1 = *(const float4*)(p + 4);
        a[kc][0] = (_Float16)v0.x; a[kc][1] = (_Float16)v0.y;
        a[kc][2] = (_Float16)v0.z; a[kc][3] = (_Float16)v0.w;
        a[kc][4] = (_Float16)v1.x; a[kc][5] = (_Float16)v1.y;
        a[kc][6] = (_Float16)v1.z; a[kc][7] = (_Float16)v1.w;
    }

    floatx4 acc[8];
#pragma unroll
    for (int i = 0; i < 8; i++) acc[i] = (floatx4){0.f, 0.f, 0.f, 0.f};

#pragma unroll
    for (int kc = 0; kc < 8; kc++)
#pragma unroll
        for (int nt = 0; nt < 8; nt++) {
            half8 b = *(const half8*)&WTw[(size_t)(nt * 16 + lo16) * FIN + kc * 32 + quad * 8];
            acc[nt] = __builtin_amdgcn_mfma_f32_16x16x32_f16(a[kc], b, acc[nt], 0, 0, 0);
        }

    const int arow = wave * 16 + quad * 4;   // C layout: row = quad*4+reg, col = lo16
    if (which < 2) {
        _Float16* outp = which == 0 ? H : H2;
#pragma unroll
        for (int nt = 0; nt < 8; nt++)
#pragma unroll
            for (int rr = 0; rr < 4; rr++)
                outp[(size_t)(r0 + arow + rr) * FOUT + nt * 16 + lo16] = (_Float16)acc[nt][rr];
    } else {
#pragma unroll
        for (int nt = 0; nt < 8; nt++) {
            half4v v;
#pragma unroll
            for (int rr = 0; rr < 4; rr++) v[rr] = (_Float16)acc[nt][rr];
            *(half4v*)&H3T[(size_t)(nt * 16 + lo16) * N + r0 + arow] = v;
        }
    }
}

// ---------------------------------------------------------------------------
// Kernel B: flash-style masked attention, online softmax, NO barriers.
// K/V B-fragments loaded directly from global (L2-hot, 2 MB tables).
// Only LDS use: per-wave P transpose (C-layout -> A-layout), 9 KB total.
// grid (N/BM, JS), block 256 (4 waves x 16 Q-rows).
// ---------------------------------------------------------------------------
template<int JS>
__global__ __launch_bounds__(256, 4)
void attn_kernel(const _Float16* __restrict__ Hq,   // [N][128]
                 const _Float16* __restrict__ Hk,   // [N][128]
                 const _Float16* __restrict__ VT,   // [128][N]
                 const int* __restrict__ adj,       // [N][N]
                 float* __restrict__ Opart,         // [JS][N][128]
                 float* __restrict__ mpart,         // [JS][N]
                 float* __restrict__ lpart)         // [JS][N]
{
    __shared__ _Float16 Ps[4][16][BN + 8];  // per-wave P [qrow][j]

    const int tid  = threadIdx.x;
    const int wave = tid >> 6;
    const int lane = tid & 63;
    const int lo16 = lane & 15;
    const int quad = lane >> 4;
    const int i0   = blockIdx.x * BM;
    const int js   = blockIdx.y;
    const int jbeg = js * (N / JS);

    // Q fragments (A-layout): row = lane&15, k = quad*8 + j
    half8 q[4];
#pragma unroll
    for (int kc = 0; kc < 4; kc++)
        q[kc] = *(const half8*)&Hq[(size_t)(i0 + wave * 16 + lo16) * FOUT + kc * 32 + quad * 8];

    floatx4 O[8];
#pragma unroll
    for (int i = 0; i < 8; i++) O[i] = (floatx4){0.f, 0.f, 0.f, 0.f};
    float m_r[4], l_r[4];
#pragma unroll
    for (int r = 0; r < 4; r++) { m_r[r] = -1e12f; l_r[r] = 0.f; }

    const int arow = i0 + wave * 16 + quad * 4;   // C-layout row base

    for (int it = 0; it < (N / JS) / BN; it++) {
        const int j0 = jbeg + it * BN;

        // adjacency (HBM, read-once): issued first, consumed after QK^T
        int am[4][4];
#pragma unroll
        for (int nt = 0; nt < 4; nt++)
#pragma unroll
            for (int r = 0; r < 4; r++)
                am[nt][r] = adj[(size_t)(arow + r) * N + j0 + nt * 16 + lo16];

        // S = Q K^T, K B-frags straight from global (L2-hot)
        floatx4 S[4];
#pragma unroll
        for (int nt = 0; nt < 4; nt++) {
            S[nt] = (floatx4){0.f, 0.f, 0.f, 0.f};
#pragma unroll
            for (int kc = 0; kc < 4; kc++) {
                half8 b = *(const half8*)&Hk[(size_t)(j0 + nt * 16 + lo16) * FOUT + kc * 32 + quad * 8];
                S[nt] = __builtin_amdgcn_mfma_f32_16x16x32_f16(q[kc], b, S[nt], 0, 0, 0);
            }
        }

        // LeakyReLU then adjacency mask (ref order)
        float sv[4][4];
#pragma unroll
        for (int nt = 0; nt < 4; nt++)
#pragma unroll
            for (int r = 0; r < 4; r++) {
                float e = S[nt][r];
                e = e > 0.f ? e : 0.2f * e;
                sv[nt][r] = am[nt][r] != 0 ? e : -1e12f;
            }

        // row max: 16-lane butterfly (C-layout row lives in 16 lanes of a quad)
        float alpha[4];
#pragma unroll
        for (int r = 0; r < 4; r++) {
            float v = fmaxf(fmaxf(sv[0][r], sv[1][r]), fmaxf(sv[2][r], sv[3][r]));
#pragma unroll
            for (int d = 1; d < 16; d <<= 1)
                v = fmaxf(v, __shfl_xor(v, d));
            float mn = fmaxf(m_r[r], v);
            alpha[r] = __expf(m_r[r] - mn);
            m_r[r] = mn;
        }

        // P = exp(sv - m); stash fp16 P in per-wave LDS (C-layout positions)
        float rs[4] = {0.f, 0.f, 0.f, 0.f};
#pragma unroll
        for (int nt = 0; nt < 4; nt++)
#pragma unroll
            for (int r = 0; r < 4; r++) {
                float p = __expf(sv[nt][r] - m_r[r]);
                rs[r] += p;
                Ps[wave][quad * 4 + r][nt * 16 + lo16] = (_Float16)p;
            }
#pragma unroll
        for (int r = 0; r < 4; r++) {
            float v = rs[r];
#pragma unroll
            for (int d = 1; d < 16; d <<= 1)
                v += __shfl_xor(v, d);
            l_r[r] = l_r[r] * alpha[r] + v;
#pragma unroll
            for (int nt = 0; nt < 8; nt++)
                O[nt][r] *= alpha[r];
        }

        // wave-private LDS transpose: drain DS writes, then read A-layout
        asm volatile("s_waitcnt lgkmcnt(0)" ::: "memory");

        // O += P V, V B-frags straight from global (L2-hot)
#pragma unroll
        for (int kc = 0; kc < BN / 32; kc++) {
            half8 pa = *(const half8*)&Ps[wave][lo16][kc * 32 + quad * 8];
#pragma unroll
            for (int nt = 0; nt < 8; nt++) {
                half8 b = *(const half8*)&VT[(size_t)(nt * 16 + lo16) * N + j0 + kc * 32 + quad * 8];
                O[nt] = __builtin_amdgcn_mfma_f32_16x16x32_f16(pa, b, O[nt], 0, 0, 0);
            }
        }
    }

    // epilogue: unnormalized O + (m, l) partials
#pragma unroll
    for (int nt = 0; nt < 8; nt++)
#pragma unroll
        for (int r = 0; r < 4; r++)
            Opart[((size_t)js * N + arow + r) * FOUT + nt * 16 + lo16] = O[nt][r];
    if (lo16 == 0) {
#pragma unroll
        for (int r = 0; r < 4; r++) {
            mpart[js * N + arow + r] = m_r[r];
            lpart[js * N + arow + r] = l_r[r];
        }
    }
}

// ---------------------------------------------------------------------------
// Kernel C: combine j-split partials, normalize, ELU, fp32 out.
// ---------------------------------------------------------------------------
template<int JS>
__global__ __launch_bounds__(256)
void combine_kernel(const float* __restrict__ Opart,
                    const float* __restrict__ mpart,
                    const float* __restrict__ lpart,
                    float* __restrict__ out)
{
    int idx = blockIdx.x * 256 + threadIdx.x;   // over N*32 float4s
    int i = idx >> 5;
    int c = (idx & 31) << 2;
    float m[JS];
    float M = -3.0e38f;
#pragma unroll
    for (int s = 0; s < JS; s++) { m[s] = mpart[s * N + i]; M = fmaxf(M, m[s]); }
    float w[JS];
    float L = 0.f;
#pragma unroll
    for (int s = 0; s < JS; s++) { w[s] = __expf(m[s] - M); L += lpart[s * N + i] * w[s]; }
    float4 o = {0.f, 0.f, 0.f, 0.f};
#pragma unroll
    for (int s = 0; s < JS; s++) {
        float4 v = *(const float4*)&Opart[((size_t)s * N + i) * FOUT + c];
        o.x += w[s] * v.x; o.y += w[s] * v.y; o.z += w[s] * v.z; o.w += w[s] * v.w;
    }
    float inv = 1.f / L;
    float r0 = o.x * inv, r1 = o.y * inv, r2 = o.z * inv, r3 = o.w * inv;
    float4 res;
    res.x = r0 > 0.f ? r0 : __expf(r0) - 1.f;
    res.y = r1 > 0.f ? r1 : __expf(r1) - 1.f;
    res.z = r2 > 0.f ? r2 : __expf(r2) - 1.f;
    res.w = r3 > 0.f ? r3 : __expf(r3) - 1.f;
    *(float4*)&out[(size_t)i * FOUT + c] = res;
}

// ---------------------------------------------------------------------------
extern "C" void kernel_launch(void* const* d_in, const int* in_sizes, int n_in,
                              void* d_out, int out_size, void* d_ws, size_t ws_size,
                              hipStream_t stream) {
    const float* inp = (const float*)d_in[0];
    const int*   adj = (const int*)d_in[1];
    const float* W0  = (const float*)d_in[2];
    const float* W1  = (const float*)d_in[3];
    const float* W2  = (const float*)d_in[4];
    float* out = (float*)d_out;

    char* ws = (char*)d_ws;
    _Float16* H   = (_Float16*)(ws);                      // 2 MB
    _Float16* H2  = (_Float16*)(ws + (2u << 20));         // 2 MB
    _Float16* H3T = (_Float16*)(ws + (4u << 20));         // 2 MB, [128][N]
    _Float16* WT  = (_Float16*)(ws + (6u << 20));         // 192 KB (3x128x256 fp16)
    float* Opart  = (float*)(ws + (8u << 20));            // JS*4 MB

    // pick JSPLIT by available workspace (constant across calls)
    const size_t need8 = (8ull << 20) + 8ull * N * FOUT * 4 + 2ull * 8 * N * 4 + (1u << 20);

    wprep_kernel<<<(3 * FIN * FOUT) / 256, 256, 0, stream>>>(W0, W1, W2, WT);
    gemm3_kernel<<<dim3(N / 64, 3), 256, 0, stream>>>(inp, WT, H, H2, H3T);

    if (ws_size >= need8) {
        constexpr int JS = 8;
        float* mpart = (float*)(ws + (8u << 20) + (size_t)JS * N * FOUT * 4);
        float* lpart = mpart + (size_t)JS * N;
        attn_kernel<JS><<<dim3(N / BM, JS), 256, 0, stream>>>(H, H2, H3T, adj, Opart, mpart, lpart);
        combine_kernel<JS><<<(N * FOUT / 4) / 256, 256, 0, stream>>>(Opart, mpart, lpart, out);
    } else {
        constexpr int JS = 4;
        float* mpart = (float*)(ws + (8u << 20) + (size_t)JS * N * FOUT * 4);
        float* lpart = mpart + (size_t)JS * N;
        attn_kernel<JS><<<dim3(N / BM, JS), 256, 0, stream>>>(H, H2, H3T, adj, Opart, mpart, lpart);
        combine_kernel<JS><<<(N * FOUT / 4) / 256, 256, 0, stream>>>(Opart, mpart, lpart, out);
    }
}